// Round 13
// baseline (3610.372 us; speedup 1.0000x reference)
//
#include <hip/hip_runtime.h>
#include <hip/hip_fp16.h>
#include <cstdint>

// Problem constants
#define T_  256
#define B_  64
#define I_  1024
#define H_  1024
#define E_  4
#define C_  128
#define G4  4096   // 4*H

typedef _Float16 f16;
typedef _Float16 f16x8 __attribute__((ext_vector_type(8)));
typedef float    f32x4 __attribute__((ext_vector_type(4)));

__device__ __forceinline__ float sigmoidf_(float x) { return 1.f / (1.f + __expf(-x)); }

// ---------------- conversion f32 -> f16 (vectorized, grid-stride) -------------
__global__ void k_f32_to_f16(const float* __restrict__ src, f16* __restrict__ dst, int n8) {
    int i = blockIdx.x * blockDim.x + threadIdx.x;
    int stride = gridDim.x * blockDim.x;
    for (; i < n8; i += stride) {
        const float4* s = reinterpret_cast<const float4*>(src) + (size_t)i * 2;
        float4 a = s[0], b = s[1];
        f16x8 v = { (f16)a.x, (f16)a.y, (f16)a.z, (f16)a.w,
                    (f16)b.x, (f16)b.y, (f16)b.z, (f16)b.w };
        *reinterpret_cast<f16x8*>(dst + (size_t)i * 8) = v;
    }
}

// ---------------- mixed biases: gbias = coef@(bi+bh), bom = coef@bo ----------
__global__ void k_mix_biases(const float* __restrict__ coef, const float* __restrict__ bi,
                             const float* __restrict__ bh, const float* __restrict__ bo,
                             float* __restrict__ gbias, float* __restrict__ bom) {
    int idx = blockIdx.x * blockDim.x + threadIdx.x;
    int stride = gridDim.x * blockDim.x;
    for (int i = idx; i < B_ * G4; i += stride) {
        int b = i >> 12, o = i & (G4 - 1);
        float s = 0.f;
#pragma unroll
        for (int e = 0; e < 4; ++e) s += coef[b * 4 + e] * (bi[e * G4 + o] + bh[e * G4 + o]);
        gbias[i] = s;
    }
    for (int i = idx; i < B_ * C_; i += stride) {
        int b = i >> 7, c = i & (C_ - 1);
        float s = 0.f;
#pragma unroll
        for (int e = 0; e < 4; ++e) s += coef[b * 4 + e] * bo[e * C_ + c];
        bom[i] = s;
    }
}

// ---------------- h0 -> f16 --------------------------------------------------
__global__ void k_init_h0h(const float* __restrict__ h0, f16* __restrict__ h0h) {
    int i = blockIdx.x * blockDim.x + threadIdx.x;
    if (i < B_ * H_) h0h[i] = (f16)h0[i];
}

// ---------------- xi GEMM: per-sample mixed input projection -----------------
template<bool XF16, bool WF16>
__global__ __launch_bounds__(256, 1) void k_xi_gemm(
        const f16* __restrict__ xh, const float* __restrict__ xf,
        const f16* __restrict__ Wih, const float* __restrict__ Wif,
        const float* __restrict__ coef, const float* __restrict__ gbias,
        f16* __restrict__ xi) {
    __shared__ f16 As[256 * 72];
    __shared__ f16 Bs[128 * 72];
    const int nt = blockIdx.x;      // 0..31  (128-col tile of 4096)
    const int b  = blockIdx.y;      // 0..63
    const int tid = threadIdx.x;
    const int lane = tid & 63, wave = tid >> 6;
    const int wr = wave >> 1, wc = wave & 1;

    float cf[4];
#pragma unroll
    for (int e = 0; e < 4; ++e) cf[e] = coef[b * 4 + e];

    f32x4 acc[8][4];
#pragma unroll
    for (int mi = 0; mi < 8; ++mi)
#pragma unroll
        for (int ni = 0; ni < 4; ++ni) acc[mi][ni] = 0.f;

    for (int kk = 0; kk < I_; kk += 64) {
        __syncthreads();
#pragma unroll
        for (int it = 0; it < 8; ++it) {
            int chunk = it * 256 + tid;
            int row = chunk >> 3, c8 = chunk & 7;
            if constexpr (XF16) {
                *reinterpret_cast<f16x8*>(&As[row * 72 + c8 * 8]) =
                    *reinterpret_cast<const f16x8*>(&xh[((size_t)row * B_ + b) * I_ + kk + c8 * 8]);
            } else {
                const float4* p = reinterpret_cast<const float4*>(&xf[((size_t)row * B_ + b) * I_ + kk + c8 * 8]);
                float4 a = p[0], bq = p[1];
                f16x8 v = { (f16)a.x, (f16)a.y, (f16)a.z, (f16)a.w,
                            (f16)bq.x, (f16)bq.y, (f16)bq.z, (f16)bq.w };
                *reinterpret_cast<f16x8*>(&As[row * 72 + c8 * 8]) = v;
            }
        }
#pragma unroll
        for (int it = 0; it < 4; ++it) {
            int chunk = it * 256 + tid;
            int n = chunk >> 3, c8 = chunk & 7;
            if constexpr (WF16) {
                size_t base = ((size_t)(nt * 128 + n)) * I_ + kk + c8 * 8;
                f16 c0 = (f16)cf[0], c1 = (f16)cf[1], c2 = (f16)cf[2], c3 = (f16)cf[3];
                f16x8 w0 = *reinterpret_cast<const f16x8*>(&Wih[base]);
                f16x8 w1 = *reinterpret_cast<const f16x8*>(&Wih[base + (size_t)1 * G4 * I_]);
                f16x8 w2 = *reinterpret_cast<const f16x8*>(&Wih[base + (size_t)2 * G4 * I_]);
                f16x8 w3 = *reinterpret_cast<const f16x8*>(&Wih[base + (size_t)3 * G4 * I_]);
                f16x8 m = w0 * c0 + w1 * c1 + w2 * c2 + w3 * c3;
                *reinterpret_cast<f16x8*>(&Bs[n * 72 + c8 * 8]) = m;
            } else {
                size_t base = ((size_t)(nt * 128 + n)) * I_ + kk + c8 * 8;
                float m[8];
#pragma unroll
                for (int j = 0; j < 8; ++j) m[j] = 0.f;
#pragma unroll
                for (int e = 0; e < 4; ++e) {
                    const float4* p = reinterpret_cast<const float4*>(&Wif[base + (size_t)e * G4 * I_]);
                    float4 a = p[0], bq = p[1];
                    m[0] += cf[e] * a.x;  m[1] += cf[e] * a.y;
                    m[2] += cf[e] * a.z;  m[3] += cf[e] * a.w;
                    m[4] += cf[e] * bq.x; m[5] += cf[e] * bq.y;
                    m[6] += cf[e] * bq.z; m[7] += cf[e] * bq.w;
                }
                f16x8 v = { (f16)m[0], (f16)m[1], (f16)m[2], (f16)m[3],
                            (f16)m[4], (f16)m[5], (f16)m[6], (f16)m[7] };
                *reinterpret_cast<f16x8*>(&Bs[n * 72 + c8 * 8]) = v;
            }
        }
        __syncthreads();
#pragma unroll
        for (int ks = 0; ks < 2; ++ks) {
            int ko = ks * 32 + (lane >> 4) * 8;
            f16x8 a[8], bb[4];
#pragma unroll
            for (int mi = 0; mi < 8; ++mi)
                a[mi] = *reinterpret_cast<const f16x8*>(&As[(wr * 128 + mi * 16 + (lane & 15)) * 72 + ko]);
#pragma unroll
            for (int ni = 0; ni < 4; ++ni)
                bb[ni] = *reinterpret_cast<const f16x8*>(&Bs[(wc * 64 + ni * 16 + (lane & 15)) * 72 + ko]);
#pragma unroll
            for (int mi = 0; mi < 8; ++mi)
#pragma unroll
                for (int ni = 0; ni < 4; ++ni)
                    acc[mi][ni] = __builtin_amdgcn_mfma_f32_16x16x32_f16(a[mi], bb[ni], acc[mi][ni], 0, 0, 0);
        }
    }
#pragma unroll
    for (int mi = 0; mi < 8; ++mi)
#pragma unroll
        for (int ni = 0; ni < 4; ++ni)
#pragma unroll
            for (int j = 0; j < 4; ++j) {
                int t = wr * 128 + mi * 16 + (lane >> 4) * 4 + j;
                int o = nt * 128 + wc * 64 + ni * 16 + (lane & 15);
                float v = acc[mi][ni][j] + gbias[b * G4 + o];
                xi[((size_t)t * B_ + b) * G4 + o] = (f16)v;
            }
}

// ---------------- barrier V3 (R11/R12-proven). The arrival RELEASE (agent) is
// what publishes this block's cached h stores to L3 before flagging. ---------
__device__ __forceinline__ void grid_barrier3(int* __restrict__ arr, int* __restrict__ go,
                                              int t, int jb) {
    __syncthreads();
    const int tid = threadIdx.x;
    if (jb == 0) {
        if (tid >= 1 && tid < 256) {              // parallel sweep, own slot each
            while (__hip_atomic_load(&arr[t * 256 + tid], __ATOMIC_RELAXED,
                                     __HIP_MEMORY_SCOPE_AGENT) == 0)
                __builtin_amdgcn_s_sleep(1);
        }
        __syncthreads();
        if (tid == 0)                             // flush master's own h (release)
            __hip_atomic_store(&go[t * 512 + 511], 1, __ATOMIC_RELEASE,
                               __HIP_MEMORY_SCOPE_AGENT);
        __syncthreads();
        if (tid < 32)                             // fan-out go: 32 lines, 8 spinners each
            __hip_atomic_store(&go[t * 512 + tid * 16], 1, __ATOMIC_RELAXED,
                               __HIP_MEMORY_SCOPE_AGENT);
        __syncthreads();
    } else {
        if (tid == 0) {
            __hip_atomic_store(&arr[t * 256 + jb], 1, __ATOMIC_RELEASE,
                               __HIP_MEMORY_SCOPE_AGENT);
            while (__hip_atomic_load(&go[t * 512 + (jb >> 3) * 16], __ATOMIC_RELAXED,
                                     __HIP_MEMORY_SCOPE_AGENT) == 0)
                __builtin_amdgcn_s_sleep(1);
        }
        __builtin_amdgcn_sched_barrier(0);
        __syncthreads();
    }
}

// ---------------- persistent recurrence (cooperative, 256 x 512) -------------
// R12 core, NO VOLATILES: h lives in a dedicated hs[T][B][H] buffer.
//  - xi is read-only after the gemm -> all gate loads cached, no hazard.
//  - h stores are plain cached stores, published by the barrier arrival's
//    agent-scope RELEASE (writes back ~512B of dirty lines to L3 - cheap).
//  - h_prev reads cached: hs[t] addresses are fresh each step (no reader L2
//    copy can predate the write; launch acquire invalidated L2s; no HW
//    speculative prefetch). First touch = L3 hit, multicast via XCD L2.
// This removes the R11/R12 system-scope HBM round trip (FETCH 2.7MB/step).
#define POOL_SZ  148480
#define AS0_OFF  131072
#define AS1_OFF  (131072 + 8192)
#define GL_OFF   131072

#define BF(KC, KS) (*reinterpret_cast<const f16x8*>(pool + wrow + (KC) * 128 + (((KS) * 64 + koff) ^ swz)))

// cached A-tile prefetch: tile KC into named reg PF
#define PRE(KC, PF) PF = *reinterpret_cast<const f16x8*>(&hprev[(size_t)sr * H_ + (KC) * 64 + soct * 8]);

#define AFR(AOFF, AROW, KS) (*reinterpret_cast<const f16x8*>(pool + (AOFF) + (AROW) + (((KS) * 64 + koff) ^ swz)))

#define MM4(ROFF) \
    acc0 = __builtin_amdgcn_mfma_f32_16x16x32_f16(AFR(ROFF, arow0, 0), bq0, acc0, 0, 0, 0); \
    acc1 = __builtin_amdgcn_mfma_f32_16x16x32_f16(AFR(ROFF, arow1, 0), bq0, acc1, 0, 0, 0); \
    acc0 = __builtin_amdgcn_mfma_f32_16x16x32_f16(AFR(ROFF, arow0, 1), bq1, acc0, 0, 0, 0); \
    acc1 = __builtin_amdgcn_mfma_f32_16x16x32_f16(AFR(ROFF, arow1, 1), bq1, acc1, 0, 0, 0);

#define KST(KC, ROFF, WOFF, PFW) { \
    const f16x8 bq0 = BF(KC, 0), bq1 = BF(KC, 1); \
    MM4(ROFF); \
    *reinterpret_cast<f16x8*>(pool + (WOFF) + sdst) = PFW; \
    __syncthreads(); \
}
#define KSTP(KC, ROFF, WOFF, PFW, PFL) { \
    const f16x8 bq0 = BF(KC, 0), bq1 = BF(KC, 1); \
    PRE((KC) + 4, PFL); \
    MM4(ROFF); \
    *reinterpret_cast<f16x8*>(pool + (WOFF) + sdst) = PFW; \
    __syncthreads(); \
}

__global__ __launch_bounds__(512, 1) void k_rec_persist(
        const float* __restrict__ Wh, const f16* __restrict__ h0h,
        const float* __restrict__ c0, const f16* __restrict__ xi,
        f16* __restrict__ hs, const float* __restrict__ coef,
        float* __restrict__ out, int* __restrict__ arr, int* __restrict__ go) {
    __shared__ __attribute__((aligned(16))) char pool[POOL_SZ];
    float* gl = reinterpret_cast<float*>(pool + GL_OFF);   // [4][64][17]

    const int jb = blockIdx.x;
    const int tid = threadIdx.x, lane = tid & 63, w = tid >> 6;
    const int ex = w & 3, mh = w >> 2;                    // expert, M-half
    const int l15 = lane & 15, hi8 = (lane >> 4) * 8;

    // ---- one-time: Wh slice f32 -> f16 into swizzled LDS ----
    for (int i = tid; i < 8192; i += 512) {
        int r = i >> 7, oct = i & 127;                    // r = e*16+g*4+c
        int e = r >> 4, g = (r >> 2) & 3, c = r & 3;
        const float* src = &Wh[((size_t)e * G4 + g * H_ + jb * 4 + c) * H_ + oct * 8];
        float4 f0 = *reinterpret_cast<const float4*>(src);
        float4 f1 = *reinterpret_cast<const float4*>(src + 4);
        f16x8 v = { (f16)f0.x, (f16)f0.y, (f16)f0.z, (f16)f0.w,
                    (f16)f1.x, (f16)f1.y, (f16)f1.z, (f16)f1.w };
        int db = r * 2048 + ((oct * 16) ^ ((r & 7) << 4));
        *reinterpret_cast<f16x8*>(pool + db) = v;
    }

    // cell-update identity (threads 0..255)
    const int bb = tid >> 2, cl = tid & 3;
    const int col = jb * 4 + cl;
    float c_reg = 0.f;
    float4 cf4 = {0.f, 0.f, 0.f, 0.f};
    if (tid < 256) {
        c_reg = c0[bb * H_ + col];
        cf4 = *reinterpret_cast<const float4*>(&coef[bb * 4]);
    }

    // per-thread LDS bases; swizzle applied to FULL within-row offset at use
    const int swz   = (l15 & 7) << 4;
    const int koff  = hi8 * 2;
    const int wrow  = (ex * 16 + l15) * 2048;
    const int arow0 = (mh * 32 + l15) * 128;
    const int arow1 = arow0 + 16 * 128;
    const int sr = tid >> 3, soct = tid & 7;
    const int sdst = sr * 128 + ((soct * 16) ^ ((sr & 7) << 4));

    __syncthreads();

    for (int t = 0; t < T_; ++t) {
        const f16* hprev = (t == 0) ? h0h : (hs + (size_t)(t - 1) * (B_ * H_));

        // xi gate operands (xi is read-only -> plain cached loads)
        float xg0 = 0.f, xg1 = 0.f, xg2 = 0.f, xg3 = 0.f;
        if (tid < 256) {
            const f16* xp = &xi[((size_t)t * B_ + bb) * G4 + col];
            xg0 = (float)xp[0];      xg1 = (float)xp[H_];
            xg2 = (float)xp[2 * H_]; xg3 = (float)xp[3 * H_];
        }

        // 4-deep cached prefetch pipeline
        f16x8 pfa, pfb, pfc, pfd;
        PRE(0, pfa) PRE(1, pfb) PRE(2, pfc) PRE(3, pfd)
        *reinterpret_cast<f16x8*>(pool + AS0_OFF + sdst) = pfa;   // tile 0
        f32x4 acc0 = {0.f, 0.f, 0.f, 0.f}, acc1 = {0.f, 0.f, 0.f, 0.f};
        __syncthreads();

        KSTP(0,  AS0_OFF, AS1_OFF, pfb, pfa)
        KSTP(1,  AS1_OFF, AS0_OFF, pfc, pfb)
        KSTP(2,  AS0_OFF, AS1_OFF, pfd, pfc)
        KSTP(3,  AS1_OFF, AS0_OFF, pfa, pfd)
        KSTP(4,  AS0_OFF, AS1_OFF, pfb, pfa)
        KSTP(5,  AS1_OFF, AS0_OFF, pfc, pfb)
        KSTP(6,  AS0_OFF, AS1_OFF, pfd, pfc)
        KSTP(7,  AS1_OFF, AS0_OFF, pfa, pfd)
        KSTP(8,  AS0_OFF, AS1_OFF, pfb, pfa)
        KSTP(9,  AS1_OFF, AS0_OFF, pfc, pfb)
        KSTP(10, AS0_OFF, AS1_OFF, pfd, pfc)
        KSTP(11, AS1_OFF, AS0_OFF, pfa, pfd)
        KST(12,  AS0_OFF, AS1_OFF, pfb)
        KST(13,  AS1_OFF, AS0_OFF, pfc)
        KST(14,  AS0_OFF, AS1_OFF, pfd)
        // tile 15: MFMA only + trailing sync (gl overlay becomes safe)
        {
            const f16x8 bq0 = BF(15, 0), bq1 = BF(15, 1);
            MM4(AS1_OFF);
            __syncthreads();
        }

        // park per-expert partials into gl (overlays As0/As1)
#pragma unroll
        for (int j = 0; j < 4; ++j) {
            int r0 = mh * 32 + (lane >> 4) * 4 + j;
            gl[(ex * 64 + r0) * 17 + l15]      = acc0[j];
            gl[(ex * 64 + r0 + 16) * 17 + l15] = acc1[j];
        }
        __syncthreads();

        // mix experts + cell update (threads 0..255); plain cached h store
        if (tid < 256) {
            float gate[4];
#pragma unroll
            for (int g = 0; g < 4; ++g) {
                int nn = g * 4 + cl;
                gate[g] = cf4.x * gl[(0 * 64 + bb) * 17 + nn] +
                          cf4.y * gl[(1 * 64 + bb) * 17 + nn] +
                          cf4.z * gl[(2 * 64 + bb) * 17 + nn] +
                          cf4.w * gl[(3 * 64 + bb) * 17 + nn];
            }
            gate[0] += xg0; gate[1] += xg1; gate[2] += xg2; gate[3] += xg3;
            float cn = sigmoidf_(gate[1]) * c_reg + sigmoidf_(gate[0]) * tanhf(gate[2]);
            float hn = sigmoidf_(gate[3]) * tanhf(cn);
            c_reg = cn;
            hs[(size_t)t * (B_ * H_) + bb * H_ + col] = (f16)hn;
            if (t == T_ - 1) {
                out[(size_t)T_ * B_ * C_ + bb * H_ + col] = hn;
                out[(size_t)T_ * B_ * C_ + B_ * H_ + bb * H_ + col] = cn;
            }
        }
        if (t != T_ - 1) grid_barrier3(arr, go, t, jb);
    }
}

// ---------------- output projection (hs is contiguous [T][B][H] now) ---------
__global__ __launch_bounds__(256, 1) void k_out_gemm(
        const f16* __restrict__ hs, const f16* __restrict__ Woh,
        const float* __restrict__ coef, const float* __restrict__ bom,
        float* __restrict__ out) {
    __shared__ f16 As[64 * 72];
    __shared__ f16 Bs[256 * 72];
    __shared__ float cfs[64][4];
    const int nt = blockIdx.x;   // 0..1
    const int t  = blockIdx.y;   // 0..255
    const int tid = threadIdx.x, lane = tid & 63, w = tid >> 6;
    cfs[tid >> 2][tid & 3] = coef[tid];

    f32x4 acc[4][4];
#pragma unroll
    for (int e = 0; e < 4; ++e)
#pragma unroll
        for (int mi = 0; mi < 4; ++mi) acc[e][mi] = 0.f;

    for (int kk = 0; kk < H_; kk += 64) {
        __syncthreads();
#pragma unroll
        for (int it = 0; it < 2; ++it) {   // A: hs[t] 64x64
            int chunk = it * 256 + tid;
            int row = chunk >> 3, c8 = chunk & 7;
            *reinterpret_cast<f16x8*>(&As[row * 72 + c8 * 8]) =
                *reinterpret_cast<const f16x8*>(&hs[(size_t)t * (B_ * H_) + (size_t)row * H_ + kk + c8 * 8]);
        }
#pragma unroll
        for (int it = 0; it < 8; ++it) {   // B: Wo rows e*C + nt*64 + n
            int chunk = it * 256 + tid;
            int r = chunk >> 3, c8 = chunk & 7;
            int e = r >> 6, nn = r & 63;
            size_t grow = (size_t)e * C_ + nt * 64 + nn;
            *reinterpret_cast<f16x8*>(&Bs[r * 72 + c8 * 8]) =
                *reinterpret_cast<const f16x8*>(&Woh[grow * H_ + kk + c8 * 8]);
        }
        __syncthreads();
#pragma unroll
        for (int ks = 0; ks < 2; ++ks) {
            int ko = ks * 32 + (lane >> 4) * 8;
            f16x8 a[4];
#pragma unroll
            for (int mi = 0; mi < 4; ++mi)
                a[mi] = *reinterpret_cast<const f16x8*>(&As[(mi * 16 + (lane & 15)) * 72 + ko]);
#pragma unroll
            for (int e = 0; e < 4; ++e) {
                f16x8 bf = *reinterpret_cast<const f16x8*>(&Bs[(e * 64 + w * 16 + (lane & 15)) * 72 + ko]);
#pragma unroll
                for (int mi = 0; mi < 4; ++mi)
                    acc[e][mi] = __builtin_amdgcn_mfma_f32_16x16x32_f16(a[mi], bf, acc[e][mi], 0, 0, 0);
            }
        }
    }
#pragma unroll
    for (int mi = 0; mi < 4; ++mi)
#pragma unroll
        for (int j = 0; j < 4; ++j) {
            int bb = mi * 16 + (lane >> 4) * 4 + j;
            int cc = nt * 64 + w * 16 + (lane & 15);
            float v = cfs[bb][0] * acc[0][mi][j] + cfs[bb][1] * acc[1][mi][j] +
                      cfs[bb][2] * acc[2][mi][j] + cfs[bb][3] * acc[3][mi][j];
            v += bom[bb * C_ + cc];
            out[((size_t)t * B_ + bb) * C_ + cc] = v;
        }
}

extern "C" void kernel_launch(void* const* d_in, const int* in_sizes, int n_in,
                              void* d_out, int out_size, void* d_ws, size_t ws_size,
                              hipStream_t stream) {
    const float* x    = (const float*)d_in[0];
    const float* h0   = (const float*)d_in[1];
    const float* c0   = (const float*)d_in[2];
    const float* coef = (const float*)d_in[3];
    const float* Wi   = (const float*)d_in[4];
    const float* bi   = (const float*)d_in[5];
    const float* Wh   = (const float*)d_in[6];
    const float* bh   = (const float*)d_in[7];
    const float* Wo   = (const float*)d_in[8];
    const float* bo   = (const float*)d_in[9];
    float* out = (float*)d_out;

    char* base = (char*)d_ws;
    size_t off = 0;
    auto carve = [&](size_t bytes) -> char* {
        char* r = base + off;
        off = (off + bytes + 255) & ~(size_t)255;
        return r;
    };
    const size_t SZ_XI  = (size_t)T_ * B_ * G4 * 2;   // 134.2 MB
    const size_t SZ_HS  = (size_t)T_ * B_ * H_ * 2;   // 33.5 MB dedicated h buffer
    const size_t SZ_WOH = (size_t)E_ * C_ * H_ * 2;   // 1 MB
    const size_t SZ_ARR = (size_t)T_ * 256 * 4;       // arrival slots
    const size_t SZ_GO  = (size_t)T_ * 512 * 4;       // go fan-out lines
    const size_t SZ_WIH = (size_t)E_ * G4 * I_ * 2;   // 33.5 MB (optional)
    const size_t SZ_XH  = (size_t)T_ * B_ * I_ * 2;   // 33.5 MB (optional)

    f16*   xi     = (f16*)carve(SZ_XI);
    f16*   hsb    = (f16*)carve(SZ_HS);
    f16*   Woh    = (f16*)carve(SZ_WOH);
    f16*   h0h    = (f16*)carve((size_t)B_ * H_ * 2);
    float* gbias  = (float*)carve((size_t)B_ * G4 * 4);
    float* bom    = (float*)carve((size_t)B_ * C_ * 4);
    int*   arr    = (int*)carve(SZ_ARR);
    int*   go     = (int*)carve(SZ_GO);

    f16* Wih = nullptr;
    f16* xh  = nullptr;
    if (off + SZ_WIH + 256 <= ws_size) Wih = (f16*)carve(SZ_WIH);
    if (Wih && off + SZ_XH + 256 <= ws_size) xh = (f16*)carve(SZ_XH);
    (void)in_sizes; (void)n_in; (void)out_size;

    hipMemsetAsync(arr, 0, SZ_ARR, stream);
    hipMemsetAsync(go, 0, SZ_GO, stream);

    if (xh)  k_f32_to_f16<<<2048, 256, 0, stream>>>(x,  xh,  (T_ * B_ * I_) / 8);
    if (Wih) k_f32_to_f16<<<2048, 256, 0, stream>>>(Wi, Wih, (E_ * G4 * I_) / 8);
    k_f32_to_f16<<<512,  256, 0, stream>>>(Wo, Woh, (E_ * C_ * H_) / 8);
    k_mix_biases<<<512, 256, 0, stream>>>(coef, bi, bh, bo, gbias, bom);
    k_init_h0h<<<(B_ * H_ + 255) / 256, 256, 0, stream>>>(h0, h0h);

    dim3 gx(32, 64);
    if (xh)
        k_xi_gemm<true,  true ><<<gx, 256, 0, stream>>>(xh, nullptr, Wih, nullptr, coef, gbias, xi);
    else if (Wih)
        k_xi_gemm<false, true ><<<gx, 256, 0, stream>>>(nullptr, x, Wih, nullptr, coef, gbias, xi);
    else
        k_xi_gemm<false, false><<<gx, 256, 0, stream>>>(nullptr, x, nullptr, Wi, coef, gbias, xi);

    // persistent recurrence: one cooperative launch, 256 blocks x 512 threads
    {
        void* args[] = { (void*)&Wh, (void*)&h0h, (void*)&c0, (void*)&xi, (void*)&hsb,
                         (void*)&coef, (void*)&out, (void*)&arr, (void*)&go };
        hipLaunchCooperativeKernel((const void*)k_rec_persist, dim3(256), dim3(512),
                                   args, 0, stream);
    }

    dim3 go_(2, 256);
    k_out_gemm<<<go_, 256, 0, stream>>>(hsb, Woh, coef, bom, out);
}

// Round 14
// 2615.802 us; speedup vs baseline: 1.3802x; 1.3802x over previous
//
#include <hip/hip_runtime.h>
#include <hip/hip_fp16.h>
#include <cstdint>

// Problem constants
#define T_  256
#define B_  64
#define I_  1024
#define H_  1024
#define E_  4
#define C_  128
#define G4  4096   // 4*H

typedef _Float16 f16;
typedef _Float16 f16x8 __attribute__((ext_vector_type(8)));
typedef float    f32x4 __attribute__((ext_vector_type(4)));

__device__ __forceinline__ float sigmoidf_(float x) { return 1.f / (1.f + __expf(-x)); }

// ---------------- conversion f32 -> f16 (vectorized, grid-stride) -------------
__global__ void k_f32_to_f16(const float* __restrict__ src, f16* __restrict__ dst, int n8) {
    int i = blockIdx.x * blockDim.x + threadIdx.x;
    int stride = gridDim.x * blockDim.x;
    for (; i < n8; i += stride) {
        const float4* s = reinterpret_cast<const float4*>(src) + (size_t)i * 2;
        float4 a = s[0], b = s[1];
        f16x8 v = { (f16)a.x, (f16)a.y, (f16)a.z, (f16)a.w,
                    (f16)b.x, (f16)b.y, (f16)b.z, (f16)b.w };
        *reinterpret_cast<f16x8*>(dst + (size_t)i * 8) = v;
    }
}

// ---------------- mixed biases: gbias = coef@(bi+bh), bom = coef@bo ----------
__global__ void k_mix_biases(const float* __restrict__ coef, const float* __restrict__ bi,
                             const float* __restrict__ bh, const float* __restrict__ bo,
                             float* __restrict__ gbias, float* __restrict__ bom) {
    int idx = blockIdx.x * blockDim.x + threadIdx.x;
    int stride = gridDim.x * blockDim.x;
    for (int i = idx; i < B_ * G4; i += stride) {
        int b = i >> 12, o = i & (G4 - 1);
        float s = 0.f;
#pragma unroll
        for (int e = 0; e < 4; ++e) s += coef[b * 4 + e] * (bi[e * G4 + o] + bh[e * G4 + o]);
        gbias[i] = s;
    }
    for (int i = idx; i < B_ * C_; i += stride) {
        int b = i >> 7, c = i & (C_ - 1);
        float s = 0.f;
#pragma unroll
        for (int e = 0; e < 4; ++e) s += coef[b * 4 + e] * bo[e * C_ + c];
        bom[i] = s;
    }
}

// ---------------- h0 -> f16 --------------------------------------------------
__global__ void k_init_h0h(const float* __restrict__ h0, f16* __restrict__ h0h) {
    int i = blockIdx.x * blockDim.x + threadIdx.x;
    if (i < B_ * H_) h0h[i] = (f16)h0[i];
}

// ---------------- xi GEMM: per-sample mixed input projection -----------------
template<bool XF16, bool WF16>
__global__ __launch_bounds__(256, 1) void k_xi_gemm(
        const f16* __restrict__ xh, const float* __restrict__ xf,
        const f16* __restrict__ Wih, const float* __restrict__ Wif,
        const float* __restrict__ coef, const float* __restrict__ gbias,
        f16* __restrict__ xi) {
    __shared__ f16 As[256 * 72];
    __shared__ f16 Bs[128 * 72];
    const int nt = blockIdx.x;      // 0..31  (128-col tile of 4096)
    const int b  = blockIdx.y;      // 0..63
    const int tid = threadIdx.x;
    const int lane = tid & 63, wave = tid >> 6;
    const int wr = wave >> 1, wc = wave & 1;

    float cf[4];
#pragma unroll
    for (int e = 0; e < 4; ++e) cf[e] = coef[b * 4 + e];

    f32x4 acc[8][4];
#pragma unroll
    for (int mi = 0; mi < 8; ++mi)
#pragma unroll
        for (int ni = 0; ni < 4; ++ni) acc[mi][ni] = 0.f;

    for (int kk = 0; kk < I_; kk += 64) {
        __syncthreads();
#pragma unroll
        for (int it = 0; it < 8; ++it) {
            int chunk = it * 256 + tid;
            int row = chunk >> 3, c8 = chunk & 7;
            if constexpr (XF16) {
                *reinterpret_cast<f16x8*>(&As[row * 72 + c8 * 8]) =
                    *reinterpret_cast<const f16x8*>(&xh[((size_t)row * B_ + b) * I_ + kk + c8 * 8]);
            } else {
                const float4* p = reinterpret_cast<const float4*>(&xf[((size_t)row * B_ + b) * I_ + kk + c8 * 8]);
                float4 a = p[0], bq = p[1];
                f16x8 v = { (f16)a.x, (f16)a.y, (f16)a.z, (f16)a.w,
                            (f16)bq.x, (f16)bq.y, (f16)bq.z, (f16)bq.w };
                *reinterpret_cast<f16x8*>(&As[row * 72 + c8 * 8]) = v;
            }
        }
#pragma unroll
        for (int it = 0; it < 4; ++it) {
            int chunk = it * 256 + tid;
            int n = chunk >> 3, c8 = chunk & 7;
            if constexpr (WF16) {
                size_t base = ((size_t)(nt * 128 + n)) * I_ + kk + c8 * 8;
                f16 c0 = (f16)cf[0], c1 = (f16)cf[1], c2 = (f16)cf[2], c3 = (f16)cf[3];
                f16x8 w0 = *reinterpret_cast<const f16x8*>(&Wih[base]);
                f16x8 w1 = *reinterpret_cast<const f16x8*>(&Wih[base + (size_t)1 * G4 * I_]);
                f16x8 w2 = *reinterpret_cast<const f16x8*>(&Wih[base + (size_t)2 * G4 * I_]);
                f16x8 w3 = *reinterpret_cast<const f16x8*>(&Wih[base + (size_t)3 * G4 * I_]);
                f16x8 m = w0 * c0 + w1 * c1 + w2 * c2 + w3 * c3;
                *reinterpret_cast<f16x8*>(&Bs[n * 72 + c8 * 8]) = m;
            } else {
                size_t base = ((size_t)(nt * 128 + n)) * I_ + kk + c8 * 8;
                float m[8];
#pragma unroll
                for (int j = 0; j < 8; ++j) m[j] = 0.f;
#pragma unroll
                for (int e = 0; e < 4; ++e) {
                    const float4* p = reinterpret_cast<const float4*>(&Wif[base + (size_t)e * G4 * I_]);
                    float4 a = p[0], bq = p[1];
                    m[0] += cf[e] * a.x;  m[1] += cf[e] * a.y;
                    m[2] += cf[e] * a.z;  m[3] += cf[e] * a.w;
                    m[4] += cf[e] * bq.x; m[5] += cf[e] * bq.y;
                    m[6] += cf[e] * bq.z; m[7] += cf[e] * bq.w;
                }
                f16x8 v = { (f16)m[0], (f16)m[1], (f16)m[2], (f16)m[3],
                            (f16)m[4], (f16)m[5], (f16)m[6], (f16)m[7] };
                *reinterpret_cast<f16x8*>(&Bs[n * 72 + c8 * 8]) = v;
            }
        }
        __syncthreads();
#pragma unroll
        for (int ks = 0; ks < 2; ++ks) {
            int ko = ks * 32 + (lane >> 4) * 8;
            f16x8 a[8], bb[4];
#pragma unroll
            for (int mi = 0; mi < 8; ++mi)
                a[mi] = *reinterpret_cast<const f16x8*>(&As[(wr * 128 + mi * 16 + (lane & 15)) * 72 + ko]);
#pragma unroll
            for (int ni = 0; ni < 4; ++ni)
                bb[ni] = *reinterpret_cast<const f16x8*>(&Bs[(wc * 64 + ni * 16 + (lane & 15)) * 72 + ko]);
#pragma unroll
            for (int mi = 0; mi < 8; ++mi)
#pragma unroll
                for (int ni = 0; ni < 4; ++ni)
                    acc[mi][ni] = __builtin_amdgcn_mfma_f32_16x16x32_f16(a[mi], bb[ni], acc[mi][ni], 0, 0, 0);
        }
    }
#pragma unroll
    for (int mi = 0; mi < 8; ++mi)
#pragma unroll
        for (int ni = 0; ni < 4; ++ni)
#pragma unroll
            for (int j = 0; j < 4; ++j) {
                int t = wr * 128 + mi * 16 + (lane >> 4) * 4 + j;
                int o = nt * 128 + wc * 64 + ni * 16 + (lane & 15);
                float v = acc[mi][ni][j] + gbias[b * G4 + o];
                xi[((size_t)t * B_ + b) * G4 + o] = (f16)v;
            }
}

// ---------------- barrier V3 (R11/R12-proven; uses raw blockIdx) -------------
__device__ __forceinline__ void grid_barrier3(int* __restrict__ arr, int* __restrict__ go,
                                              int t, int bid) {
    __syncthreads();
    const int tid = threadIdx.x;
    if (bid == 0) {
        if (tid >= 1 && tid < 256) {              // parallel sweep, own slot each
            while (__hip_atomic_load(&arr[t * 256 + tid], __ATOMIC_RELAXED,
                                     __HIP_MEMORY_SCOPE_AGENT) == 0)
                __builtin_amdgcn_s_sleep(1);
        }
        __syncthreads();
        if (tid == 0)                             // flush master's own h (release)
            __hip_atomic_store(&go[t * 512 + 511], 1, __ATOMIC_RELEASE,
                               __HIP_MEMORY_SCOPE_AGENT);
        __syncthreads();
        if (tid < 32)                             // fan-out go: 32 lines, 8 spinners each
            __hip_atomic_store(&go[t * 512 + tid * 16], 1, __ATOMIC_RELAXED,
                               __HIP_MEMORY_SCOPE_AGENT);
        __syncthreads();
    } else {
        if (tid == 0) {
            __hip_atomic_store(&arr[t * 256 + bid], 1, __ATOMIC_RELEASE,
                               __HIP_MEMORY_SCOPE_AGENT);
            while (__hip_atomic_load(&go[t * 512 + (bid >> 3) * 16], __ATOMIC_RELAXED,
                                     __HIP_MEMORY_SCOPE_AGENT) == 0)
                __builtin_amdgcn_s_sleep(1);
        }
        __builtin_amdgcn_sched_barrier(0);
        __syncthreads();
    }
}

// ---------------- persistent recurrence (cooperative, 256 x 512) -------------
// R12 core + two deltas:
//  (1) XCD-contiguous col-ownership: jb = (bid&7)*32 + (bid>>3). XCD x owns
//      h-cols x*128..+128, so the 8 blocks sharing each 64B gate/h line are
//      on ONE XCD -> 1 L2 miss + 7 hits instead of 8 cross-XCD line fetches.
//  (2) gate double-buffer: step t+1's xg loaded during step t's K-loop (fully
//      hidden). xgn0 volatile (gate-0 line = future h line; a cached copy
//      would go stale after the h overlay write - same audit as R12's xg0).
// Everything else identical to R12 (volatile h store, cached h_prev PRE,
// barrier V3, W in swizzled LDS).
#define POOL_SZ  148480
#define AS0_OFF  131072
#define AS1_OFF  (131072 + 8192)
#define GL_OFF   131072

#define BF(KC, KS) (*reinterpret_cast<const f16x8*>(pool + wrow + (KC) * 128 + (((KS) * 64 + koff) ^ swz)))

// cached A-tile prefetch: tile KC into named reg PF
#define PRE(KC, PF) PF = *reinterpret_cast<const f16x8*>(&hprev[(size_t)sr * hstr + (KC) * 64 + soct * 8]);

#define AFR(AOFF, AROW, KS) (*reinterpret_cast<const f16x8*>(pool + (AOFF) + (AROW) + (((KS) * 64 + koff) ^ swz)))

#define MM4(ROFF) \
    acc0 = __builtin_amdgcn_mfma_f32_16x16x32_f16(AFR(ROFF, arow0, 0), bq0, acc0, 0, 0, 0); \
    acc1 = __builtin_amdgcn_mfma_f32_16x16x32_f16(AFR(ROFF, arow1, 0), bq0, acc1, 0, 0, 0); \
    acc0 = __builtin_amdgcn_mfma_f32_16x16x32_f16(AFR(ROFF, arow0, 1), bq1, acc0, 0, 0, 0); \
    acc1 = __builtin_amdgcn_mfma_f32_16x16x32_f16(AFR(ROFF, arow1, 1), bq1, acc1, 0, 0, 0);

#define KST(KC, ROFF, WOFF, PFW) { \
    const f16x8 bq0 = BF(KC, 0), bq1 = BF(KC, 1); \
    MM4(ROFF); \
    *reinterpret_cast<f16x8*>(pool + (WOFF) + sdst) = PFW; \
    __syncthreads(); \
}
#define KSTP(KC, ROFF, WOFF, PFW, PFL) { \
    const f16x8 bq0 = BF(KC, 0), bq1 = BF(KC, 1); \
    PRE((KC) + 4, PFL); \
    MM4(ROFF); \
    *reinterpret_cast<f16x8*>(pool + (WOFF) + sdst) = PFW; \
    __syncthreads(); \
}

__global__ __launch_bounds__(512, 1) void k_rec_persist(
        const float* __restrict__ Wh, const f16* __restrict__ h0h,
        const float* __restrict__ c0, f16* xi, const float* __restrict__ coef,
        float* __restrict__ out, int* __restrict__ arr, int* __restrict__ go) {
    __shared__ __attribute__((aligned(16))) char pool[POOL_SZ];
    float* gl = reinterpret_cast<float*>(pool + GL_OFF);   // [4][64][17]

    const int bid = blockIdx.x;
    const int jb = ((bid & 7) << 5) | (bid >> 3);          // XCD-contiguous cols
    const int tid = threadIdx.x, lane = tid & 63, w = tid >> 6;
    const int ex = w & 3, mh = w >> 2;                    // expert, M-half
    const int l15 = lane & 15, hi8 = (lane >> 4) * 8;

    // ---- one-time: Wh slice f32 -> f16 into swizzled LDS ----
    for (int i = tid; i < 8192; i += 512) {
        int r = i >> 7, oct = i & 127;                    // r = e*16+g*4+c
        int e = r >> 4, g = (r >> 2) & 3, c = r & 3;
        const float* src = &Wh[((size_t)e * G4 + g * H_ + jb * 4 + c) * H_ + oct * 8];
        float4 f0 = *reinterpret_cast<const float4*>(src);
        float4 f1 = *reinterpret_cast<const float4*>(src + 4);
        f16x8 v = { (f16)f0.x, (f16)f0.y, (f16)f0.z, (f16)f0.w,
                    (f16)f1.x, (f16)f1.y, (f16)f1.z, (f16)f1.w };
        int db = r * 2048 + ((oct * 16) ^ ((r & 7) << 4));
        *reinterpret_cast<f16x8*>(pool + db) = v;
    }

    // cell-update identity (threads 0..255)
    const int bb = tid >> 2, cl = tid & 3;
    const int col = jb * 4 + cl;
    float c_reg = 0.f;
    float4 cf4 = {0.f, 0.f, 0.f, 0.f};
    if (tid < 256) {
        c_reg = c0[bb * H_ + col];
        cf4 = *reinterpret_cast<const float4*>(&coef[bb * 4]);
    }

    // per-thread LDS bases; swizzle applied to FULL within-row offset at use
    const int swz   = (l15 & 7) << 4;
    const int koff  = hi8 * 2;
    const int wrow  = (ex * 16 + l15) * 2048;
    const int arow0 = (mh * 32 + l15) * 128;
    const int arow1 = arow0 + 16 * 128;
    const int sr = tid >> 3, soct = tid & 7;
    const int sdst = sr * 128 + ((soct * 16) ^ ((sr & 7) << 4));

    __syncthreads();

    // gate double-buffer: load step-0 gates (xg0 volatile: h-overlay line)
    float xgc0 = 0.f, xgc1 = 0.f, xgc2 = 0.f, xgc3 = 0.f;
    if (tid < 256) {
        const f16* xp = &xi[((size_t)0 * B_ + bb) * G4 + col];
        xgc0 = (float)*reinterpret_cast<const volatile f16*>(&xp[0]);
        xgc1 = (float)xp[H_];
        xgc2 = (float)xp[2 * H_]; xgc3 = (float)xp[3 * H_];
    }

    for (int t = 0; t < T_; ++t) {
        const f16* hprev = (t == 0) ? h0h : (xi + (size_t)(t - 1) * B_ * G4);
        const size_t hstr = (t == 0) ? (size_t)H_ : (size_t)G4;

        // prefetch NEXT step's gates (consumed at t+1; ~one full step of slack)
        float xgn0 = 0.f, xgn1 = 0.f, xgn2 = 0.f, xgn3 = 0.f;
        if (t + 1 < T_ && tid < 256) {
            const f16* xq = &xi[((size_t)(t + 1) * B_ + bb) * G4 + col];
            xgn0 = (float)*reinterpret_cast<const volatile f16*>(&xq[0]);
            xgn1 = (float)xq[H_];
            xgn2 = (float)xq[2 * H_]; xgn3 = (float)xq[3 * H_];
        }

        // 4-deep cached prefetch pipeline
        f16x8 pfa, pfb, pfc, pfd;
        PRE(0, pfa) PRE(1, pfb) PRE(2, pfc) PRE(3, pfd)
        *reinterpret_cast<f16x8*>(pool + AS0_OFF + sdst) = pfa;   // tile 0
        f32x4 acc0 = {0.f, 0.f, 0.f, 0.f}, acc1 = {0.f, 0.f, 0.f, 0.f};
        __syncthreads();

        KSTP(0,  AS0_OFF, AS1_OFF, pfb, pfa)
        KSTP(1,  AS1_OFF, AS0_OFF, pfc, pfb)
        KSTP(2,  AS0_OFF, AS1_OFF, pfd, pfc)
        KSTP(3,  AS1_OFF, AS0_OFF, pfa, pfd)
        KSTP(4,  AS0_OFF, AS1_OFF, pfb, pfa)
        KSTP(5,  AS1_OFF, AS0_OFF, pfc, pfb)
        KSTP(6,  AS0_OFF, AS1_OFF, pfd, pfc)
        KSTP(7,  AS1_OFF, AS0_OFF, pfa, pfd)
        KSTP(8,  AS0_OFF, AS1_OFF, pfb, pfa)
        KSTP(9,  AS1_OFF, AS0_OFF, pfc, pfb)
        KSTP(10, AS0_OFF, AS1_OFF, pfd, pfc)
        KSTP(11, AS1_OFF, AS0_OFF, pfa, pfd)
        KST(12,  AS0_OFF, AS1_OFF, pfb)
        KST(13,  AS1_OFF, AS0_OFF, pfc)
        KST(14,  AS0_OFF, AS1_OFF, pfd)
        // tile 15: MFMA only + trailing sync (gl overlay becomes safe)
        {
            const f16x8 bq0 = BF(15, 0), bq1 = BF(15, 1);
            MM4(AS1_OFF);
            __syncthreads();
        }

        // park per-expert partials into gl (overlays As0/As1)
#pragma unroll
        for (int j = 0; j < 4; ++j) {
            int r0 = mh * 32 + (lane >> 4) * 4 + j;
            gl[(ex * 64 + r0) * 17 + l15]      = acc0[j];
            gl[(ex * 64 + r0 + 16) * 17 + l15] = acc1[j];
        }
        __syncthreads();

        // mix experts + cell update (threads 0..255); h store is VOLATILE
        if (tid < 256) {
            float gate[4];
#pragma unroll
            for (int g = 0; g < 4; ++g) {
                int nn = g * 4 + cl;
                gate[g] = cf4.x * gl[(0 * 64 + bb) * 17 + nn] +
                          cf4.y * gl[(1 * 64 + bb) * 17 + nn] +
                          cf4.z * gl[(2 * 64 + bb) * 17 + nn] +
                          cf4.w * gl[(3 * 64 + bb) * 17 + nn];
            }
            gate[0] += xgc0; gate[1] += xgc1; gate[2] += xgc2; gate[3] += xgc3;
            float cn = sigmoidf_(gate[1]) * c_reg + sigmoidf_(gate[0]) * tanhf(gate[2]);
            float hn = sigmoidf_(gate[3]) * tanhf(cn);
            c_reg = cn;
            *reinterpret_cast<volatile f16*>(&xi[((size_t)t * B_ + bb) * G4 + col]) = (f16)hn;
            if (t == T_ - 1) {
                out[(size_t)T_ * B_ * C_ + bb * H_ + col] = hn;
                out[(size_t)T_ * B_ * C_ + B_ * H_ + bb * H_ + col] = cn;
            }
        }
        xgc0 = xgn0; xgc1 = xgn1; xgc2 = xgn2; xgc3 = xgn3;
        if (t != T_ - 1) grid_barrier3(arr, go, t, bid);
    }
}

// ---------------- output projection ------------------------------------------
__global__ __launch_bounds__(256, 1) void k_out_gemm(
        const f16* __restrict__ hs, const f16* __restrict__ Woh,
        const float* __restrict__ coef, const float* __restrict__ bom,
        float* __restrict__ out) {
    __shared__ f16 As[64 * 72];
    __shared__ f16 Bs[256 * 72];
    __shared__ float cfs[64][4];
    const int nt = blockIdx.x;   // 0..1
    const int t  = blockIdx.y;   // 0..255
    const int tid = threadIdx.x, lane = tid & 63, w = tid >> 6;
    cfs[tid >> 2][tid & 3] = coef[tid];

    f32x4 acc[4][4];
#pragma unroll
    for (int e = 0; e < 4; ++e)
#pragma unroll
        for (int mi = 0; mi < 4; ++mi) acc[e][mi] = 0.f;

    for (int kk = 0; kk < H_; kk += 64) {
        __syncthreads();
#pragma unroll
        for (int it = 0; it < 2; ++it) {   // A: hs[t] 64x64 (stride G4 overlay)
            int chunk = it * 256 + tid;
            int row = chunk >> 3, c8 = chunk & 7;
            *reinterpret_cast<f16x8*>(&As[row * 72 + c8 * 8]) =
                *reinterpret_cast<const f16x8*>(&hs[((size_t)t * B_ + row) * G4 + kk + c8 * 8]);
        }
#pragma unroll
        for (int it = 0; it < 8; ++it) {   // B: Wo rows e*C + nt*64 + n
            int chunk = it * 256 + tid;
            int r = chunk >> 3, c8 = chunk & 7;
            int e = r >> 6, nn = r & 63;
            size_t grow = (size_t)e * C_ + nt * 64 + nn;
            *reinterpret_cast<f16x8*>(&Bs[r * 72 + c8 * 8]) =
                *reinterpret_cast<const f16x8*>(&Woh[grow * H_ + kk + c8 * 8]);
        }
        __syncthreads();
#pragma unroll
        for (int ks = 0; ks < 2; ++ks) {
            int ko = ks * 32 + (lane >> 4) * 8;
            f16x8 a[4];
#pragma unroll
            for (int mi = 0; mi < 4; ++mi)
                a[mi] = *reinterpret_cast<const f16x8*>(&As[(mi * 16 + (lane & 15)) * 72 + ko]);
#pragma unroll
            for (int e = 0; e < 4; ++e) {
                f16x8 bf = *reinterpret_cast<const f16x8*>(&Bs[(e * 64 + w * 16 + (lane & 15)) * 72 + ko]);
#pragma unroll
                for (int mi = 0; mi < 4; ++mi)
                    acc[e][mi] = __builtin_amdgcn_mfma_f32_16x16x32_f16(a[mi], bf, acc[e][mi], 0, 0, 0);
            }
        }
    }
#pragma unroll
    for (int mi = 0; mi < 4; ++mi)
#pragma unroll
        for (int j = 0; j < 4; ++j) {
            int bb = mi * 16 + (lane >> 4) * 4 + j;
            int cc = nt * 64 + w * 16 + (lane & 15);
            float v = cfs[bb][0] * acc[0][mi][j] + cfs[bb][1] * acc[1][mi][j] +
                      cfs[bb][2] * acc[2][mi][j] + cfs[bb][3] * acc[3][mi][j];
            v += bom[bb * C_ + cc];
            out[((size_t)t * B_ + bb) * C_ + cc] = v;
        }
}

extern "C" void kernel_launch(void* const* d_in, const int* in_sizes, int n_in,
                              void* d_out, int out_size, void* d_ws, size_t ws_size,
                              hipStream_t stream) {
    const float* x    = (const float*)d_in[0];
    const float* h0   = (const float*)d_in[1];
    const float* c0   = (const float*)d_in[2];
    const float* coef = (const float*)d_in[3];
    const float* Wi   = (const float*)d_in[4];
    const float* bi   = (const float*)d_in[5];
    const float* Wh   = (const float*)d_in[6];
    const float* bh   = (const float*)d_in[7];
    const float* Wo   = (const float*)d_in[8];
    const float* bo   = (const float*)d_in[9];
    float* out = (float*)d_out;

    char* base = (char*)d_ws;
    size_t off = 0;
    auto carve = [&](size_t bytes) -> char* {
        char* r = base + off;
        off = (off + bytes + 255) & ~(size_t)255;
        return r;
    };
    const size_t SZ_XI  = (size_t)T_ * B_ * G4 * 2;   // 134.2 MB (gate-0 doubles as hs)
    const size_t SZ_WOH = (size_t)E_ * C_ * H_ * 2;   // 1 MB
    const size_t SZ_ARR = (size_t)T_ * 256 * 4;       // arrival slots
    const size_t SZ_GO  = (size_t)T_ * 512 * 4;       // go fan-out lines
    const size_t SZ_WIH = (size_t)E_ * G4 * I_ * 2;   // 33.5 MB (optional)
    const size_t SZ_XH  = (size_t)T_ * B_ * I_ * 2;   // 33.5 MB (optional)

    f16*   xi     = (f16*)carve(SZ_XI);
    f16*   Woh    = (f16*)carve(SZ_WOH);
    f16*   h0h    = (f16*)carve((size_t)B_ * H_ * 2);
    float* gbias  = (float*)carve((size_t)B_ * G4 * 4);
    float* bom    = (float*)carve((size_t)B_ * C_ * 4);
    int*   arr    = (int*)carve(SZ_ARR);
    int*   go     = (int*)carve(SZ_GO);

    f16* Wih = nullptr;
    f16* xh  = nullptr;
    if (off + SZ_WIH + 256 <= ws_size) Wih = (f16*)carve(SZ_WIH);
    if (Wih && off + SZ_XH + 256 <= ws_size) xh = (f16*)carve(SZ_XH);
    (void)in_sizes; (void)n_in; (void)out_size;

    hipMemsetAsync(arr, 0, SZ_ARR, stream);
    hipMemsetAsync(go, 0, SZ_GO, stream);

    if (xh)  k_f32_to_f16<<<2048, 256, 0, stream>>>(x,  xh,  (T_ * B_ * I_) / 8);
    if (Wih) k_f32_to_f16<<<2048, 256, 0, stream>>>(Wi, Wih, (E_ * G4 * I_) / 8);
    k_f32_to_f16<<<512,  256, 0, stream>>>(Wo, Woh, (E_ * C_ * H_) / 8);
    k_mix_biases<<<512, 256, 0, stream>>>(coef, bi, bh, bo, gbias, bom);
    k_init_h0h<<<(B_ * H_ + 255) / 256, 256, 0, stream>>>(h0, h0h);

    dim3 gx(32, 64);
    if (xh)
        k_xi_gemm<true,  true ><<<gx, 256, 0, stream>>>(xh, nullptr, Wih, nullptr, coef, gbias, xi);
    else if (Wih)
        k_xi_gemm<false, true ><<<gx, 256, 0, stream>>>(nullptr, x, Wih, nullptr, coef, gbias, xi);
    else
        k_xi_gemm<false, false><<<gx, 256, 0, stream>>>(nullptr, x, nullptr, Wi, coef, gbias, xi);

    // persistent recurrence: one cooperative launch, 256 blocks x 512 threads
    {
        void* args[] = { (void*)&Wh, (void*)&h0h, (void*)&c0, (void*)&xi,
                         (void*)&coef, (void*)&out, (void*)&arr, (void*)&go };
        hipLaunchCooperativeKernel((const void*)k_rec_persist, dim3(256), dim3(512),
                                   args, 0, stream);
    }

    dim3 go_(2, 256);
    k_out_gemm<<<go_, 256, 0, stream>>>(xi, Woh, coef, bom, out);
}